// Round 19
// baseline (86.374 us; speedup 1.0000x reference)
//
#include <hip/hip_runtime.h>
#include <hip/hip_bf16.h>

typedef __attribute__((ext_vector_type(8))) short short8;
typedef __attribute__((ext_vector_type(4))) float f32x4;
typedef __attribute__((ext_vector_type(4))) unsigned int u32x4;
typedef unsigned short u16;
typedef unsigned int   u32;
typedef unsigned long long u64;
typedef unsigned char  u8;

#define NN 8192
#define THRESH 0.1f

__device__ __forceinline__ u16 f2bf(float f){
  __hip_bfloat16 h = __float2bfloat16(f);
  u16 u; __builtin_memcpy(&u, &h, 2); return u;
}
__device__ __forceinline__ float bf2f(u16 h){
  u32 u = ((u32)h) << 16;
  return __builtin_bit_cast(float, u);
}

// ---- K1 (fused norm + mask + deg-count): swapped-operand MFMA mask, 32 i-rows/wave.
// Each block normalizes + hi/lo-splits the 640 rows it needs (128 i + 512 j) into LDS
// (fragment-major [blk][slice g][row n][8], byte-identical semantics to the old global
// snT), then runs the proven R15 mask loop against LDS. Row degrees accumulate as
// INTEGER popcount atomics (deterministic). Replaces k_norm + k_maskM2 + k_deg. ----
__global__ __launch_bounds__(256) void k_maskM2F(const float* __restrict__ st, u32* __restrict__ maskT,
                                                 u32* __restrict__ degcnt){
  __shared__ __align__(16) u16 ldsJ[32*512];   // 512 j-rows: 32 16-row blocks x 1KB
  __shared__ __align__(16) u16 ldsI[8*512];    // 128 i-rows: 8 16-row blocks x 1KB
  int tid = threadIdx.x;
  int lane = tid & 63, wid = tid >> 6;
  int n = lane & 15, g = lane >> 4;
  int bid = (int)blockIdx.x;                   // 0..1023 = 64 i-blocks x 16 j-chunks
  int i0b = (bid >> 4) * 128;
  int jc  = (bid & 15) * 512;
  int i0w = i0b + wid * 32;

  // normalize row ROW of st, write hi/lo fragment-major into DSTBASE (u16*, 512 per 16-block)
#define NORMROW(ROW, DST) do { \
    const float4* s4_ = reinterpret_cast<const float4*>(st + (size_t)(ROW)*16); \
    float4 v_[4]; float ss_ = 0.f; \
    _Pragma("unroll") \
    for (int q=0;q<4;q++){ v_[q]=s4_[q]; ss_ += v_[q].x*v_[q].x+v_[q].y*v_[q].y+v_[q].z*v_[q].z+v_[q].w*v_[q].w; } \
    float inv_ = 1.0f/(sqrtf(ss_) + 1e-12f); \
    float f_[16]; \
    _Pragma("unroll") \
    for (int q=0;q<4;q++){ f_[4*q]=v_[q].x*inv_; f_[4*q+1]=v_[q].y*inv_; f_[4*q+2]=v_[q].z*inv_; f_[4*q+3]=v_[q].w*inv_; } \
    u16 hb_[16], lb_[16]; \
    _Pragma("unroll") \
    for (int k=0;k<16;k++){ u16 h_ = f2bf(f_[k]); hb_[k] = h_; lb_[k] = f2bf(f_[k] - bf2f(h_)); } \
    u16* d_ = (DST); \
    short8 o_; \
    _Pragma("unroll") \
    for (int e=0;e<8;e++) o_[e] = (short)hb_[e]; \
    *reinterpret_cast<short8*>(d_)       = o_; \
    _Pragma("unroll") \
    for (int e=0;e<8;e++) o_[e] = (short)hb_[8+e]; \
    *reinterpret_cast<short8*>(d_ + 128) = o_; \
    _Pragma("unroll") \
    for (int e=0;e<8;e++) o_[e] = (short)lb_[e]; \
    *reinterpret_cast<short8*>(d_ + 256) = o_; \
    _Pragma("unroll") \
    for (int e=0;e<8;e++) o_[e] = (short)lb_[8+e]; \
    *reinterpret_cast<short8*>(d_ + 384) = o_; \
  } while(0)

  {
    int lj0 = tid;          // j-local rows tid and tid+256
    int lj1 = tid + 256;
    NORMROW(jc + lj0, ldsJ + (lj0 >> 4)*512 + (lj0 & 15)*8);
    NORMROW(jc + lj1, ldsJ + (lj1 >> 4)*512 + (lj1 & 15)*8);
    if (tid < 128)
      NORMROW(i0b + tid, ldsI + (tid >> 4)*512 + (tid & 15)*8);
  }
#undef NORMROW
  __syncthreads();

  // B fragments (two 16-row pairs of this wave's 32 i-rows)
  short8 b1[2], b2[2];
  #pragma unroll
  for (int p=0; p<2; ++p){
    const u16* bblk = ldsI + (wid*2 + p)*512;
    b1[p] = *reinterpret_cast<const short8*>(bblk + (g&1)*128 + n*8);        // [hi|hi]
    b2[p] = *reinterpret_cast<const short8*>(bblk + (2+(g&1))*128 + n*8);    // [lo|lo]
  }

  u32 bitc[2][4];
  #pragma unroll
  for (int h=0; h<2; ++h)
    #pragma unroll
    for (int q=0; q<4; ++q) bitc[h][q] = 1u << (h*16 + 4*g + q);

  int ii0 = i0w + n, ii1 = i0w + 16 + n;
  u32 pc0 = 0, pc1 = 0;

  #pragma unroll 2
  for (int jw2 = 0; jw2 < 16; ++jw2){
    int j0 = jc + jw2*32;
    u32 w0 = 0, w1 = 0;
    #pragma unroll
    for (int h=0; h<2; ++h){
      short8 a = *reinterpret_cast<const short8*>(ldsJ + (jw2*2 + h)*512 + lane*8);
      f32x4 acc0 = {0.f,0.f,0.f,0.f};
      f32x4 acc1 = {0.f,0.f,0.f,0.f};
      acc0 = __builtin_amdgcn_mfma_f32_16x16x32_bf16(a, b2[0], acc0, 0, 0, 0);
      acc1 = __builtin_amdgcn_mfma_f32_16x16x32_bf16(a, b2[1], acc1, 0, 0, 0);
      acc0 = __builtin_amdgcn_mfma_f32_16x16x32_bf16(a, b1[0], acc0, 0, 0, 0);
      acc1 = __builtin_amdgcn_mfma_f32_16x16x32_bf16(a, b1[1], acc1, 0, 0, 0);
      #pragma unroll
      for (int q=0;q<4;q++){
        float d0 = acc0[q], d1 = acc1[q];
        w0 |= (d0*d0 >= THRESH) ? bitc[h][q] : 0u;
        w1 |= (d1*d1 >= THRESH) ? bitc[h][q] : 0u;
      }
    }
    w0 |= __shfl_xor(w0, 16);
    w0 |= __shfl_xor(w0, 32);
    w1 |= __shfl_xor(w1, 16);
    w1 |= __shfl_xor(w1, 32);
    int jw = j0 >> 5;
    if ((ii0 >> 5) == jw) w0 &= ~(1u << (ii0 & 31));
    if ((ii1 >> 5) == jw) w1 &= ~(1u << (ii1 & 31));
    if (lane < 16){
      maskT[(size_t)jw*NN + ii0] = w0;
      maskT[(size_t)jw*NN + ii1] = w1;
      pc0 += __popc(w0);
      pc1 += __popc(w1);
    }
  }
  if (lane < 16){
    atomicAdd(&degcnt[ii0], pc0);
    atomicAdd(&degcnt[ii1], pc1);
  }
}

// ---- K3: Yt[f][j] = dinv[j] * sum_k X[j,k]*W[f,k]  (bf16, j-contiguous).
// dinv computed inline from integer degcnt (same FP expression as old k_deg -> same bits). ----
__global__ __launch_bounds__(128) void k_ygemm(const float* __restrict__ X, const float* __restrict__ W,
                                               const u32* __restrict__ degcnt, u16* __restrict__ Yt){
  int tid = threadIdx.x;
  int lane = tid & 63;
  int r = lane & 15, g = lane >> 4;
  int wj = tid >> 6;
  int f0 = blockIdx.x * 32;
  int j0 = blockIdx.y * 128 + wj * 64;
  f32x4 acc[2][4] = {};
  #pragma unroll
  for (int k0 = 0; k0 < 256; k0 += 32){
    short8 a[2], b[4];
    #pragma unroll
    for (int af=0; af<2; af++){
      const float* p = W + (f0 + af*16 + r)*256 + k0 + g*8;
      float4 u = reinterpret_cast<const float4*>(p)[0];
      float4 v = reinterpret_cast<const float4*>(p)[1];
      short8 tt;
      tt[0]=(short)f2bf(u.x); tt[1]=(short)f2bf(u.y); tt[2]=(short)f2bf(u.z); tt[3]=(short)f2bf(u.w);
      tt[4]=(short)f2bf(v.x); tt[5]=(short)f2bf(v.y); tt[6]=(short)f2bf(v.z); tt[7]=(short)f2bf(v.w);
      a[af] = tt;
    }
    #pragma unroll
    for (int bf=0; bf<4; bf++){
      const float* p = X + (j0 + bf*16 + r)*256 + k0 + g*8;
      float4 u = reinterpret_cast<const float4*>(p)[0];
      float4 v = reinterpret_cast<const float4*>(p)[1];
      short8 tt;
      tt[0]=(short)f2bf(u.x); tt[1]=(short)f2bf(u.y); tt[2]=(short)f2bf(u.z); tt[3]=(short)f2bf(u.w);
      tt[4]=(short)f2bf(v.x); tt[5]=(short)f2bf(v.y); tt[6]=(short)f2bf(v.z); tt[7]=(short)f2bf(v.w);
      b[bf] = tt;
    }
    #pragma unroll
    for (int af=0; af<2; af++)
      #pragma unroll
      for (int bf=0; bf<4; bf++)
        acc[af][bf] = __builtin_amdgcn_mfma_f32_16x16x32_bf16(a[af], b[bf], acc[af][bf], 0, 0, 0);
  }
  float ds[4];
  #pragma unroll
  for (int bf=0;bf<4;bf++){
    u32 dg = degcnt[j0 + bf*16 + r];
    ds[bf] = 1.0f/((float)dg + 1e-6f);
  }
  #pragma unroll
  for (int af=0; af<2; af++)
    #pragma unroll
    for (int bf=0; bf<4; bf++)
      #pragma unroll
      for (int q=0;q<4;q++)
        Yt[(f0 + af*16 + g*4 + q)*NN + j0 + bf*16 + r] = f2bf(acc[af][bf][q] * ds[bf]);
}

// ---- K4: partial[z] = M @ Y (bf16 out). R15/R18 proven version (~42us, 818 TF).
// Block m256 x n128, 8 waves wm4 x wn2, wave = m64 x n64. Grid 512 = 2 blocks/CU.
// 3-buffer depth-2 counted-vmcnt(3) DMA pipeline, 54KB LDS. ----
#define VMCNT(N) asm volatile("s_waitcnt vmcnt(" #N ")" ::: "memory")
__global__ __launch_bounds__(512, 4) void k_agg(const u16* __restrict__ Yt, const u32* __restrict__ maskT,
                                                u16* __restrict__ part){
  __shared__ u8  ldsB[3][16384];
  __shared__ u32 ldsM[3][512];
  int tid = threadIdx.x;
  int lane = tid & 63, wid = tid >> 6;
  int r = lane & 15, g = lane >> 4;
  int wm = wid >> 1, wn = wid & 1;
  int bid = (int)blockIdx.x;
  int gq = bid & 15;
  int m0 = (bid >> 4) * 256;
  int n0 = (gq & 1) * 128;
  int zz = gq >> 1;
  int kbase = zz * 1024;
  f32x4 acc[4][4] = {};

  const char* ytb[2];
  #pragma unroll
  for (int is=0; is<2; ++is){
    int rw = wid*16 + is*8 + (lane>>3);
    ytb[is] = (const char*)(Yt + ((size_t)(n0+rw) << 13) + (size_t)kbase + (size_t)(((lane&7) ^ (rw&7))<<3));
  }
  const char* mkb = (const char*)(maskT + (size_t)((kbase>>5) + (lane&1))*NN + m0 + wid*32 + (lane>>1));

#define GSTAGE(BUF, T) do { \
    _Pragma("unroll") \
    for (int is=0; is<2; ++is) \
      __builtin_amdgcn_global_load_lds((const __attribute__((address_space(1))) void*)(ytb[is] + (T)*128), \
          (__attribute__((address_space(3))) void*)&ldsB[BUF][wid*2048 + is*1024], 16, 0, 0); \
    __builtin_amdgcn_global_load_lds((const __attribute__((address_space(1))) void*)(mkb + (size_t)(T)*65536), \
        (__attribute__((address_space(3))) void*)&ldsM[BUF][wid*64], 4, 0, 0); \
  } while(0)

#define COMPUTE(BUF) do { \
    short8 bfrag[2][4]; \
    _Pragma("unroll") \
    for (int kk=0; kk<2; ++kk) \
      _Pragma("unroll") \
      for (int nf=0; nf<4; ++nf){ \
        int row = wn*64 + nf*16 + r; \
        bfrag[kk][nf] = *reinterpret_cast<const short8*>(&ldsB[BUF][row*128 + (((kk*4+g) ^ (row&7))<<4)]); \
      } \
    __builtin_amdgcn_s_setprio(1); \
    _Pragma("unroll") \
    for (int mf=0; mf<4; ++mf){ \
      int rowm = wm*64 + mf*16 + r; \
      u64 mw = *reinterpret_cast<const u64*>(&ldsM[BUF][rowm*2]); \
      _Pragma("unroll") \
      for (int kk=0; kk<2; ++kk){ \
        u32 byte = ((u32)(mw >> (kk*32)) >> (g*8)) & 0xffu; \
        u32 x = byte * 0x8001u; \
        u32x4 wv; \
        _Pragma("unroll") \
        for (int pp=0; pp<4; ++pp) wv[pp] = ((x >> (2*pp)) & 0x00010001u) * 0x3F80u; \
        short8 a = __builtin_bit_cast(short8, wv); \
        _Pragma("unroll") \
        for (int nf=0; nf<4; ++nf) \
          acc[mf][nf] = __builtin_amdgcn_mfma_f32_16x16x32_bf16(a, bfrag[kk][nf], acc[mf][nf], 0, 0, 0); \
      } \
    } \
    __builtin_amdgcn_s_setprio(0); \
  } while(0)

#define BODY(CB, SB, T) do { \
    GSTAGE(SB, (T)+2); \
    COMPUTE(CB); \
    VMCNT(3); \
    __builtin_amdgcn_s_barrier(); \
  } while(0)

  GSTAGE(0, 0);
  GSTAGE(1, 1);
  VMCNT(3);
  __builtin_amdgcn_s_barrier();

  #pragma unroll 1
  for (int t = 0; t < 12; t += 3){
    BODY(0, 2, t);
    BODY(1, 0, t+1);
    BODY(2, 1, t+2);
  }
  BODY(0, 2, 12);
  BODY(1, 0, 13);
  COMPUTE(2);
  VMCNT(0);
  __builtin_amdgcn_s_barrier();
  COMPUTE(0);

#undef GSTAGE
#undef COMPUTE
#undef BODY

  u16* dst = part + (size_t)zz * (NN*256);
  #pragma unroll
  for (int mf=0; mf<4; mf++)
    #pragma unroll
    for (int nf=0; nf<4; nf++)
      #pragma unroll
      for (int q=0;q<4;q++){
        int row = m0 + wm*64 + mf*16 + g*4 + q;
        int col = n0 + wn*64 + nf*16 + r;
        dst[row*256 + col] = f2bf(acc[mf][nf][q]);
      }
}

// ---- K5: out = bias + sum_z bf16 partial[z] ----
__global__ __launch_bounds__(256) void k_reduce(const u16* __restrict__ part, const float* __restrict__ bias,
                                                float* __restrict__ out){
  int i = blockIdx.x*256 + threadIdx.x;
  float4 bb = reinterpret_cast<const float4*>(bias)[i & 63];
  float a0 = bb.x, a1 = bb.y, a2 = bb.z, a3 = bb.w;
  #pragma unroll
  for (int z=0; z<8; ++z){
    u64 v = *reinterpret_cast<const u64*>(part + (size_t)z*2097152 + (size_t)i*4);
    a0 += bf2f((u16)(v      ));
    a1 += bf2f((u16)(v >> 16));
    a2 += bf2f((u16)(v >> 32));
    a3 += bf2f((u16)(v >> 48));
  }
  float4 o; o.x=a0; o.y=a1; o.z=a2; o.w=a3;
  reinterpret_cast<float4*>(out)[i] = o;
}

extern "C" void kernel_launch(void* const* d_in, const int* in_sizes, int n_in,
                              void* d_out, int out_size, void* d_ws, size_t ws_size,
                              hipStream_t stream) {
  const float* X    = (const float*)d_in[0];
  const float* S    = (const float*)d_in[1];
  const float* W    = (const float*)d_in[2];
  const float* bias = (const float*)d_in[3];
  float* out = (float*)d_out;
  char* ws = (char*)d_ws;
  u32*   maskT  = (u32*)(ws + 0);          //  8 MiB  [256 jwords][8192 i]
  u16*   Yt     = (u16*)(ws + 8388608);    //  4 MiB  bf16 [256 f][8192 j]
  u32*   degcnt = (u32*)(ws + 12582912);   //  32 KiB integer degrees
  u16*   part   = (u16*)(ws + 13139968);   //  32 MiB bf16 [8][8192][256]

  hipMemsetAsync(degcnt, 0, 8192*sizeof(u32), stream);
  k_maskM2F<<<dim3(1024), dim3(256), 0, stream>>>(S, maskT, degcnt);
  k_ygemm  <<<dim3(8,64), dim3(128), 0, stream>>>(X, W, degcnt, Yt);
  k_agg    <<<dim3(512),  dim3(512), 0, stream>>>(Yt, maskT, part);
  k_reduce <<<dim3(2048), dim3(256), 0, stream>>>(part, bias, out);
}

// Round 20
// 85.937 us; speedup vs baseline: 1.0051x; 1.0051x over previous
//
#include <hip/hip_runtime.h>
#include <hip/hip_bf16.h>

typedef __attribute__((ext_vector_type(8))) short short8;
typedef __attribute__((ext_vector_type(4))) float f32x4;
typedef __attribute__((ext_vector_type(4))) unsigned int u32x4;
typedef unsigned short u16;
typedef unsigned int   u32;
typedef unsigned long long u64;
typedef unsigned char  u8;

#define NN 8192
#define THRESH 0.1f

__device__ __forceinline__ u16 f2bf(float f){
  __hip_bfloat16 h = __float2bfloat16(f);
  u16 u; __builtin_memcpy(&u, &h, 2); return u;
}
__device__ __forceinline__ float bf2f(u16 h){
  u32 u = ((u32)h) << 16;
  return __builtin_bit_cast(float, u);
}

// ---- K1: normalize rows; bf16 hi/lo split, FRAGMENT-MAJOR: snT[b=i>>4][slice g][n=i&15][8] ----
__global__ __launch_bounds__(256) void k_norm(const float* __restrict__ st, u16* __restrict__ snT){
  int i = blockIdx.x*256 + threadIdx.x;
  const float4* s4 = reinterpret_cast<const float4*>(st + i*16);
  float4 v[4]; float ss = 0.f;
  #pragma unroll
  for (int q=0;q<4;q++){ v[q]=s4[q]; ss += v[q].x*v[q].x+v[q].y*v[q].y+v[q].z*v[q].z+v[q].w*v[q].w; }
  float inv = 1.0f/(sqrtf(ss) + 1e-12f);
  float f[16];
  #pragma unroll
  for (int q=0;q<4;q++){ f[4*q]=v[q].x*inv; f[4*q+1]=v[q].y*inv; f[4*q+2]=v[q].z*inv; f[4*q+3]=v[q].w*inv; }
  u16 hb[16], lb[16];
  #pragma unroll
  for (int k=0;k<16;k++){
    u16 h = f2bf(f[k]);
    hb[k] = h;
    lb[k] = f2bf(f[k] - bf2f(h));
  }
  u16* dst = snT + (size_t)(i >> 4)*512 + (i & 15)*8;
  short8 o;
  #pragma unroll
  for (int e=0;e<8;e++) o[e] = (short)hb[e];
  *reinterpret_cast<short8*>(dst)       = o;
  #pragma unroll
  for (int e=0;e<8;e++) o[e] = (short)hb[8+e];
  *reinterpret_cast<short8*>(dst + 128) = o;
  #pragma unroll
  for (int e=0;e<8;e++) o[e] = (short)lb[e];
  *reinterpret_cast<short8*>(dst + 256) = o;
  #pragma unroll
  for (int e=0;e<8;e++) o[e] = (short)lb[8+e];
  *reinterpret_cast<short8*>(dst + 384) = o;
}

// ---- K2: swapped-operand MFMA mask (measured ~13.7us) + integer deg popcount atomics.
// R20: only change vs R18's maskM2 is the pc accumulation + 2 atomicAdds per wave
// (deterministic integer adds; 16 blocks touch each row). Replaces k_deg. ----
__global__ __launch_bounds__(256, 6) void k_maskM2(const u16* __restrict__ snT, u32* __restrict__ maskT,
                                                   u32* __restrict__ degcnt){
  int tid = threadIdx.x;
  int lane = tid & 63, wid = tid >> 6;
  int n = lane & 15, g = lane >> 4;
  int bid = (int)blockIdx.x;                   // 0..1023
  int i0w = (bid >> 4) * 128 + wid * 32;
  int jc = (bid & 15) * 512;

  short8 b1[2], b2[2];
  #pragma unroll
  for (int p=0; p<2; ++p){
    const u16* bblk = snT + (size_t)((i0w >> 4) + p)*512;
    b1[p] = *reinterpret_cast<const short8*>(bblk + (g&1)*128 + n*8);        // [hi|hi]
    b2[p] = *reinterpret_cast<const short8*>(bblk + (2+(g&1))*128 + n*8);    // [lo|lo]
  }

  u32 bitc[2][4];
  #pragma unroll
  for (int h=0; h<2; ++h)
    #pragma unroll
    for (int q=0; q<4; ++q) bitc[h][q] = 1u << (h*16 + 4*g + q);

  int ii0 = i0w + n, ii1 = i0w + 16 + n;
  u32 pc0 = 0, pc1 = 0;

  #pragma unroll 2
  for (int jw2 = 0; jw2 < 16; ++jw2){
    int j0 = jc + jw2*32;
    u32 w0 = 0, w1 = 0;
    #pragma unroll
    for (int h=0; h<2; ++h){
      short8 a = *reinterpret_cast<const short8*>(snT + (size_t)((j0 >> 4) + h)*512 + lane*8);
      f32x4 acc0 = {0.f,0.f,0.f,0.f};
      f32x4 acc1 = {0.f,0.f,0.f,0.f};
      acc0 = __builtin_amdgcn_mfma_f32_16x16x32_bf16(a, b2[0], acc0, 0, 0, 0);
      acc1 = __builtin_amdgcn_mfma_f32_16x16x32_bf16(a, b2[1], acc1, 0, 0, 0);
      acc0 = __builtin_amdgcn_mfma_f32_16x16x32_bf16(a, b1[0], acc0, 0, 0, 0);
      acc1 = __builtin_amdgcn_mfma_f32_16x16x32_bf16(a, b1[1], acc1, 0, 0, 0);
      #pragma unroll
      for (int q=0;q<4;q++){
        float d0 = acc0[q], d1 = acc1[q];
        w0 |= (d0*d0 >= THRESH) ? bitc[h][q] : 0u;
        w1 |= (d1*d1 >= THRESH) ? bitc[h][q] : 0u;
      }
    }
    w0 |= __shfl_xor(w0, 16);
    w0 |= __shfl_xor(w0, 32);
    w1 |= __shfl_xor(w1, 16);
    w1 |= __shfl_xor(w1, 32);
    int jw = j0 >> 5;
    if ((ii0 >> 5) == jw) w0 &= ~(1u << (ii0 & 31));
    if ((ii1 >> 5) == jw) w1 &= ~(1u << (ii1 & 31));
    if (lane < 16){
      maskT[(size_t)jw*NN + ii0] = w0;
      maskT[(size_t)jw*NN + ii1] = w1;
      pc0 += __popc(w0);
      pc1 += __popc(w1);
    }
  }
  if (lane < 16){
    atomicAdd(&degcnt[ii0], pc0);
    atomicAdd(&degcnt[ii1], pc1);
  }
}

// ---- K3: Yt[f][j] = dinv[j] * sum_k X[j,k]*W[f,k]  (bf16, j-contiguous).
// dinv inline from integer degcnt (same FP expression as old k_deg -> same bits). ----
__global__ __launch_bounds__(128) void k_ygemm(const float* __restrict__ X, const float* __restrict__ W,
                                               const u32* __restrict__ degcnt, u16* __restrict__ Yt){
  int tid = threadIdx.x;
  int lane = tid & 63;
  int r = lane & 15, g = lane >> 4;
  int wj = tid >> 6;
  int f0 = blockIdx.x * 32;
  int j0 = blockIdx.y * 128 + wj * 64;
  f32x4 acc[2][4] = {};
  #pragma unroll
  for (int k0 = 0; k0 < 256; k0 += 32){
    short8 a[2], b[4];
    #pragma unroll
    for (int af=0; af<2; af++){
      const float* p = W + (f0 + af*16 + r)*256 + k0 + g*8;
      float4 u = reinterpret_cast<const float4*>(p)[0];
      float4 v = reinterpret_cast<const float4*>(p)[1];
      short8 tt;
      tt[0]=(short)f2bf(u.x); tt[1]=(short)f2bf(u.y); tt[2]=(short)f2bf(u.z); tt[3]=(short)f2bf(u.w);
      tt[4]=(short)f2bf(v.x); tt[5]=(short)f2bf(v.y); tt[6]=(short)f2bf(v.z); tt[7]=(short)f2bf(v.w);
      a[af] = tt;
    }
    #pragma unroll
    for (int bf=0; bf<4; bf++){
      const float* p = X + (j0 + bf*16 + r)*256 + k0 + g*8;
      float4 u = reinterpret_cast<const float4*>(p)[0];
      float4 v = reinterpret_cast<const float4*>(p)[1];
      short8 tt;
      tt[0]=(short)f2bf(u.x); tt[1]=(short)f2bf(u.y); tt[2]=(short)f2bf(u.z); tt[3]=(short)f2bf(u.w);
      tt[4]=(short)f2bf(v.x); tt[5]=(short)f2bf(v.y); tt[6]=(short)f2bf(v.z); tt[7]=(short)f2bf(v.w);
      b[bf] = tt;
    }
    #pragma unroll
    for (int af=0; af<2; af++)
      #pragma unroll
      for (int bf=0; bf<4; bf++)
        acc[af][bf] = __builtin_amdgcn_mfma_f32_16x16x32_bf16(a[af], b[bf], acc[af][bf], 0, 0, 0);
  }
  float ds[4];
  #pragma unroll
  for (int bf=0;bf<4;bf++){
    u32 dg = degcnt[j0 + bf*16 + r];
    ds[bf] = 1.0f/((float)dg + 1e-6f);
  }
  #pragma unroll
  for (int af=0; af<2; af++)
    #pragma unroll
    for (int bf=0; bf<4; bf++)
      #pragma unroll
      for (int q=0;q<4;q++)
        Yt[(f0 + af*16 + g*4 + q)*NN + j0 + bf*16 + r] = f2bf(acc[af][bf][q] * ds[bf]);
}

// ---- K4: partial[z] = M @ Y (bf16 out). R15/R18 proven version (~42us, 818 TF).
// Block m256 x n128, 8 waves wm4 x wn2, wave = m64 x n64. Grid 512 = 2 blocks/CU.
// 3-buffer depth-2 counted-vmcnt(3) DMA pipeline, 54KB LDS. ----
#define VMCNT(N) asm volatile("s_waitcnt vmcnt(" #N ")" ::: "memory")
__global__ __launch_bounds__(512, 4) void k_agg(const u16* __restrict__ Yt, const u32* __restrict__ maskT,
                                                u16* __restrict__ part){
  __shared__ u8  ldsB[3][16384];
  __shared__ u32 ldsM[3][512];
  int tid = threadIdx.x;
  int lane = tid & 63, wid = tid >> 6;
  int r = lane & 15, g = lane >> 4;
  int wm = wid >> 1, wn = wid & 1;
  int bid = (int)blockIdx.x;
  int gq = bid & 15;
  int m0 = (bid >> 4) * 256;
  int n0 = (gq & 1) * 128;
  int zz = gq >> 1;
  int kbase = zz * 1024;
  f32x4 acc[4][4] = {};

  const char* ytb[2];
  #pragma unroll
  for (int is=0; is<2; ++is){
    int rw = wid*16 + is*8 + (lane>>3);
    ytb[is] = (const char*)(Yt + ((size_t)(n0+rw) << 13) + (size_t)kbase + (size_t)(((lane&7) ^ (rw&7))<<3));
  }
  const char* mkb = (const char*)(maskT + (size_t)((kbase>>5) + (lane&1))*NN + m0 + wid*32 + (lane>>1));

#define GSTAGE(BUF, T) do { \
    _Pragma("unroll") \
    for (int is=0; is<2; ++is) \
      __builtin_amdgcn_global_load_lds((const __attribute__((address_space(1))) void*)(ytb[is] + (T)*128), \
          (__attribute__((address_space(3))) void*)&ldsB[BUF][wid*2048 + is*1024], 16, 0, 0); \
    __builtin_amdgcn_global_load_lds((const __attribute__((address_space(1))) void*)(mkb + (size_t)(T)*65536), \
        (__attribute__((address_space(3))) void*)&ldsM[BUF][wid*64], 4, 0, 0); \
  } while(0)

#define COMPUTE(BUF) do { \
    short8 bfrag[2][4]; \
    _Pragma("unroll") \
    for (int kk=0; kk<2; ++kk) \
      _Pragma("unroll") \
      for (int nf=0; nf<4; ++nf){ \
        int row = wn*64 + nf*16 + r; \
        bfrag[kk][nf] = *reinterpret_cast<const short8*>(&ldsB[BUF][row*128 + (((kk*4+g) ^ (row&7))<<4)]); \
      } \
    __builtin_amdgcn_s_setprio(1); \
    _Pragma("unroll") \
    for (int mf=0; mf<4; ++mf){ \
      int rowm = wm*64 + mf*16 + r; \
      u64 mw = *reinterpret_cast<const u64*>(&ldsM[BUF][rowm*2]); \
      _Pragma("unroll") \
      for (int kk=0; kk<2; ++kk){ \
        u32 byte = ((u32)(mw >> (kk*32)) >> (g*8)) & 0xffu; \
        u32 x = byte * 0x8001u; \
        u32x4 wv; \
        _Pragma("unroll") \
        for (int pp=0; pp<4; ++pp) wv[pp] = ((x >> (2*pp)) & 0x00010001u) * 0x3F80u; \
        short8 a = __builtin_bit_cast(short8, wv); \
        _Pragma("unroll") \
        for (int nf=0; nf<4; ++nf) \
          acc[mf][nf] = __builtin_amdgcn_mfma_f32_16x16x32_bf16(a, bfrag[kk][nf], acc[mf][nf], 0, 0, 0); \
      } \
    } \
    __builtin_amdgcn_s_setprio(0); \
  } while(0)

#define BODY(CB, SB, T) do { \
    GSTAGE(SB, (T)+2); \
    COMPUTE(CB); \
    VMCNT(3); \
    __builtin_amdgcn_s_barrier(); \
  } while(0)

  GSTAGE(0, 0);
  GSTAGE(1, 1);
  VMCNT(3);
  __builtin_amdgcn_s_barrier();

  #pragma unroll 1
  for (int t = 0; t < 12; t += 3){
    BODY(0, 2, t);
    BODY(1, 0, t+1);
    BODY(2, 1, t+2);
  }
  BODY(0, 2, 12);
  BODY(1, 0, 13);
  COMPUTE(2);
  VMCNT(0);
  __builtin_amdgcn_s_barrier();
  COMPUTE(0);

#undef GSTAGE
#undef COMPUTE
#undef BODY

  u16* dst = part + (size_t)zz * (NN*256);
  #pragma unroll
  for (int mf=0; mf<4; mf++)
    #pragma unroll
    for (int nf=0; nf<4; nf++)
      #pragma unroll
      for (int q=0;q<4;q++){
        int row = m0 + wm*64 + mf*16 + g*4 + q;
        int col = n0 + wn*64 + nf*16 + r;
        dst[row*256 + col] = f2bf(acc[mf][nf][q]);
      }
}

// ---- K5: out = bias + sum_z bf16 partial[z] ----
__global__ __launch_bounds__(256) void k_reduce(const u16* __restrict__ part, const float* __restrict__ bias,
                                                float* __restrict__ out){
  int i = blockIdx.x*256 + threadIdx.x;
  float4 bb = reinterpret_cast<const float4*>(bias)[i & 63];
  float a0 = bb.x, a1 = bb.y, a2 = bb.z, a3 = bb.w;
  #pragma unroll
  for (int z=0; z<8; ++z){
    u64 v = *reinterpret_cast<const u64*>(part + (size_t)z*2097152 + (size_t)i*4);
    a0 += bf2f((u16)(v      ));
    a1 += bf2f((u16)(v >> 16));
    a2 += bf2f((u16)(v >> 32));
    a3 += bf2f((u16)(v >> 48));
  }
  float4 o; o.x=a0; o.y=a1; o.z=a2; o.w=a3;
  reinterpret_cast<float4*>(out)[i] = o;
}

extern "C" void kernel_launch(void* const* d_in, const int* in_sizes, int n_in,
                              void* d_out, int out_size, void* d_ws, size_t ws_size,
                              hipStream_t stream) {
  const float* X    = (const float*)d_in[0];
  const float* S    = (const float*)d_in[1];
  const float* W    = (const float*)d_in[2];
  const float* bias = (const float*)d_in[3];
  float* out = (float*)d_out;
  char* ws = (char*)d_ws;
  u32*   maskT  = (u32*)(ws + 0);          //  8 MiB  [256 jwords][8192 i]
  u16*   Yt     = (u16*)(ws + 8388608);    //  4 MiB  bf16 [256 f][8192 j]
  u16*   snT    = (u16*)(ws + 12582912);   // 512 KiB bf16 hi/lo split, fragment-major
  u32*   degcnt = (u32*)(ws + 13107200);   //  32 KiB integer degrees
  u16*   part   = (u16*)(ws + 13139968);   //  32 MiB bf16 [8][8192][256]

  hipMemsetAsync(degcnt, 0, 8192*sizeof(u32), stream);
  k_norm  <<<dim3(32),   dim3(256), 0, stream>>>(S, snT);
  k_maskM2<<<dim3(1024), dim3(256), 0, stream>>>(snT, maskT, degcnt);
  k_ygemm <<<dim3(8,64), dim3(128), 0, stream>>>(X, W, degcnt, Yt);
  k_agg   <<<dim3(512),  dim3(512), 0, stream>>>(Yt, maskT, part);
  k_reduce<<<dim3(2048), dim3(256), 0, stream>>>(part, bias, out);
}

// Round 21
// 79.520 us; speedup vs baseline: 1.0862x; 1.0807x over previous
//
#include <hip/hip_runtime.h>
#include <hip/hip_bf16.h>

typedef __attribute__((ext_vector_type(8))) short short8;
typedef __attribute__((ext_vector_type(4))) float f32x4;
typedef __attribute__((ext_vector_type(4))) unsigned int u32x4;
typedef unsigned short u16;
typedef unsigned int   u32;
typedef unsigned long long u64;
typedef unsigned char  u8;

#define NN 8192
#define THRESH 0.1f

__device__ __forceinline__ u16 f2bf(float f){
  __hip_bfloat16 h = __float2bfloat16(f);
  u16 u; __builtin_memcpy(&u, &h, 2); return u;
}
__device__ __forceinline__ float bf2f(u16 h){
  u32 u = ((u32)h) << 16;
  return __builtin_bit_cast(float, u);
}

// ---- K1: normalize rows; bf16 hi/lo split, FRAGMENT-MAJOR: snT[b=i>>4][slice g][n=i&15][8] ----
__global__ __launch_bounds__(256) void k_norm(const float* __restrict__ st, u16* __restrict__ snT){
  int i = blockIdx.x*256 + threadIdx.x;
  const float4* s4 = reinterpret_cast<const float4*>(st + i*16);
  float4 v[4]; float ss = 0.f;
  #pragma unroll
  for (int q=0;q<4;q++){ v[q]=s4[q]; ss += v[q].x*v[q].x+v[q].y*v[q].y+v[q].z*v[q].z+v[q].w*v[q].w; }
  float inv = 1.0f/(sqrtf(ss) + 1e-12f);
  float f[16];
  #pragma unroll
  for (int q=0;q<4;q++){ f[4*q]=v[q].x*inv; f[4*q+1]=v[q].y*inv; f[4*q+2]=v[q].z*inv; f[4*q+3]=v[q].w*inv; }
  u16 hb[16], lb[16];
  #pragma unroll
  for (int k=0;k<16;k++){
    u16 h = f2bf(f[k]);
    hb[k] = h;
    lb[k] = f2bf(f[k] - bf2f(h));
  }
  u16* dst = snT + (size_t)(i >> 4)*512 + (i & 15)*8;
  short8 o;
  #pragma unroll
  for (int e=0;e<8;e++) o[e] = (short)hb[e];
  *reinterpret_cast<short8*>(dst)       = o;
  #pragma unroll
  for (int e=0;e<8;e++) o[e] = (short)hb[8+e];
  *reinterpret_cast<short8*>(dst + 128) = o;
  #pragma unroll
  for (int e=0;e<8;e++) o[e] = (short)lb[e];
  *reinterpret_cast<short8*>(dst + 256) = o;
  #pragma unroll
  for (int e=0;e<8;e++) o[e] = (short)lb[8+e];
  *reinterpret_cast<short8*>(dst + 384) = o;
}

// ---- K2: swapped-operand MFMA mask (~13.7us) + integer deg popcount atomics ----
__global__ __launch_bounds__(256, 6) void k_maskM2(const u16* __restrict__ snT, u32* __restrict__ maskT,
                                                   u32* __restrict__ degcnt){
  int tid = threadIdx.x;
  int lane = tid & 63, wid = tid >> 6;
  int n = lane & 15, g = lane >> 4;
  int bid = (int)blockIdx.x;                   // 0..1023
  int i0w = (bid >> 4) * 128 + wid * 32;
  int jc = (bid & 15) * 512;

  short8 b1[2], b2[2];
  #pragma unroll
  for (int p=0; p<2; ++p){
    const u16* bblk = snT + (size_t)((i0w >> 4) + p)*512;
    b1[p] = *reinterpret_cast<const short8*>(bblk + (g&1)*128 + n*8);        // [hi|hi]
    b2[p] = *reinterpret_cast<const short8*>(bblk + (2+(g&1))*128 + n*8);    // [lo|lo]
  }

  u32 bitc[2][4];
  #pragma unroll
  for (int h=0; h<2; ++h)
    #pragma unroll
    for (int q=0; q<4; ++q) bitc[h][q] = 1u << (h*16 + 4*g + q);

  int ii0 = i0w + n, ii1 = i0w + 16 + n;
  u32 pc0 = 0, pc1 = 0;

  #pragma unroll 2
  for (int jw2 = 0; jw2 < 16; ++jw2){
    int j0 = jc + jw2*32;
    u32 w0 = 0, w1 = 0;
    #pragma unroll
    for (int h=0; h<2; ++h){
      short8 a = *reinterpret_cast<const short8*>(snT + (size_t)((j0 >> 4) + h)*512 + lane*8);
      f32x4 acc0 = {0.f,0.f,0.f,0.f};
      f32x4 acc1 = {0.f,0.f,0.f,0.f};
      acc0 = __builtin_amdgcn_mfma_f32_16x16x32_bf16(a, b2[0], acc0, 0, 0, 0);
      acc1 = __builtin_amdgcn_mfma_f32_16x16x32_bf16(a, b2[1], acc1, 0, 0, 0);
      acc0 = __builtin_amdgcn_mfma_f32_16x16x32_bf16(a, b1[0], acc0, 0, 0, 0);
      acc1 = __builtin_amdgcn_mfma_f32_16x16x32_bf16(a, b1[1], acc1, 0, 0, 0);
      #pragma unroll
      for (int q=0;q<4;q++){
        float d0 = acc0[q], d1 = acc1[q];
        w0 |= (d0*d0 >= THRESH) ? bitc[h][q] : 0u;
        w1 |= (d1*d1 >= THRESH) ? bitc[h][q] : 0u;
      }
    }
    w0 |= __shfl_xor(w0, 16);
    w0 |= __shfl_xor(w0, 32);
    w1 |= __shfl_xor(w1, 16);
    w1 |= __shfl_xor(w1, 32);
    int jw = j0 >> 5;
    if ((ii0 >> 5) == jw) w0 &= ~(1u << (ii0 & 31));
    if ((ii1 >> 5) == jw) w1 &= ~(1u << (ii1 & 31));
    if (lane < 16){
      maskT[(size_t)jw*NN + ii0] = w0;
      maskT[(size_t)jw*NN + ii1] = w1;
      pc0 += __popc(w0);
      pc1 += __popc(w1);
    }
  }
  if (lane < 16){
    atomicAdd(&degcnt[ii0], pc0);
    atomicAdd(&degcnt[ii1], pc1);
  }
}

// ---- K3: Yt[f][j] = dinv[j] * sum_k X[j,k]*W[f,k]  (bf16, j-contiguous) ----
__global__ __launch_bounds__(128) void k_ygemm(const float* __restrict__ X, const float* __restrict__ W,
                                               const u32* __restrict__ degcnt, u16* __restrict__ Yt){
  int tid = threadIdx.x;
  int lane = tid & 63;
  int r = lane & 15, g = lane >> 4;
  int wj = tid >> 6;
  int f0 = blockIdx.x * 32;
  int j0 = blockIdx.y * 128 + wj * 64;
  f32x4 acc[2][4] = {};
  #pragma unroll
  for (int k0 = 0; k0 < 256; k0 += 32){
    short8 a[2], b[4];
    #pragma unroll
    for (int af=0; af<2; af++){
      const float* p = W + (f0 + af*16 + r)*256 + k0 + g*8;
      float4 u = reinterpret_cast<const float4*>(p)[0];
      float4 v = reinterpret_cast<const float4*>(p)[1];
      short8 tt;
      tt[0]=(short)f2bf(u.x); tt[1]=(short)f2bf(u.y); tt[2]=(short)f2bf(u.z); tt[3]=(short)f2bf(u.w);
      tt[4]=(short)f2bf(v.x); tt[5]=(short)f2bf(v.y); tt[6]=(short)f2bf(v.z); tt[7]=(short)f2bf(v.w);
      a[af] = tt;
    }
    #pragma unroll
    for (int bf=0; bf<4; bf++){
      const float* p = X + (j0 + bf*16 + r)*256 + k0 + g*8;
      float4 u = reinterpret_cast<const float4*>(p)[0];
      float4 v = reinterpret_cast<const float4*>(p)[1];
      short8 tt;
      tt[0]=(short)f2bf(u.x); tt[1]=(short)f2bf(u.y); tt[2]=(short)f2bf(u.z); tt[3]=(short)f2bf(u.w);
      tt[4]=(short)f2bf(v.x); tt[5]=(short)f2bf(v.y); tt[6]=(short)f2bf(v.z); tt[7]=(short)f2bf(v.w);
      b[bf] = tt;
    }
    #pragma unroll
    for (int af=0; af<2; af++)
      #pragma unroll
      for (int bf=0; bf<4; bf++)
        acc[af][bf] = __builtin_amdgcn_mfma_f32_16x16x32_bf16(a[af], b[bf], acc[af][bf], 0, 0, 0);
  }
  float ds[4];
  #pragma unroll
  for (int bf=0;bf<4;bf++){
    u32 dg = degcnt[j0 + bf*16 + r];
    ds[bf] = 1.0f/((float)dg + 1e-6f);
  }
  #pragma unroll
  for (int af=0; af<2; af++)
    #pragma unroll
    for (int bf=0; bf<4; bf++)
      #pragma unroll
      for (int q=0;q<4;q++)
        Yt[(f0 + af*16 + g*4 + q)*NN + j0 + bf*16 + r] = f2bf(acc[af][bf][q] * ds[bf]);
}

// ---- K4: partial[z] = M @ Y (bf16 out). R21: wave reshaped m64x64 -> m32x128
// (mf2, nf8): mask-expansion VALU per MFMA = 1/nf -> HALVED (VALUBusy was > MfmaUtil
// in every profile). kk-outer loop keeps only 8 bfrags live (VGPR ~same). Per-acc
// accumulation order over (t,kk) unchanged -> bit-identical output. Same grid/
// staging/3-buffer counted-vmcnt pipeline as R15/R18. ----
#define VMCNT(N) asm volatile("s_waitcnt vmcnt(" #N ")" ::: "memory")
__global__ __launch_bounds__(512, 4) void k_agg(const u16* __restrict__ Yt, const u32* __restrict__ maskT,
                                                u16* __restrict__ part){
  __shared__ u8  ldsB[3][16384];
  __shared__ u32 ldsM[3][512];
  int tid = threadIdx.x;
  int lane = tid & 63, wid = tid >> 6;
  int r = lane & 15, g = lane >> 4;
  int bid = (int)blockIdx.x;
  int gq = bid & 15;
  int m0 = (bid >> 4) * 256;
  int n0 = (gq & 1) * 128;
  int zz = gq >> 1;
  int kbase = zz * 1024;
  f32x4 acc[2][8] = {};                         // [mf][nf], wave = m32 x n128

  const char* ytb[2];
  #pragma unroll
  for (int is=0; is<2; ++is){
    int rw = wid*16 + is*8 + (lane>>3);
    ytb[is] = (const char*)(Yt + ((size_t)(n0+rw) << 13) + (size_t)kbase + (size_t)(((lane&7) ^ (rw&7))<<3));
  }
  const char* mkb = (const char*)(maskT + (size_t)((kbase>>5) + (lane&1))*NN + m0 + wid*32 + (lane>>1));

#define GSTAGE(BUF, T) do { \
    _Pragma("unroll") \
    for (int is=0; is<2; ++is) \
      __builtin_amdgcn_global_load_lds((const __attribute__((address_space(1))) void*)(ytb[is] + (T)*128), \
          (__attribute__((address_space(3))) void*)&ldsB[BUF][wid*2048 + is*1024], 16, 0, 0); \
    __builtin_amdgcn_global_load_lds((const __attribute__((address_space(1))) void*)(mkb + (size_t)(T)*65536), \
        (__attribute__((address_space(3))) void*)&ldsM[BUF][wid*64], 4, 0, 0); \
  } while(0)

#define COMPUTE(BUF) do { \
    __builtin_amdgcn_s_setprio(1); \
    _Pragma("unroll") \
    for (int kk=0; kk<2; ++kk){ \
      short8 bfrag[8]; \
      _Pragma("unroll") \
      for (int nf=0; nf<8; ++nf){ \
        int row = nf*16 + r; \
        bfrag[nf] = *reinterpret_cast<const short8*>(&ldsB[BUF][row*128 + (((kk*4+g) ^ (row&7))<<4)]); \
      } \
      _Pragma("unroll") \
      for (int mf=0; mf<2; ++mf){ \
        int rowm = wid*32 + mf*16 + r; \
        u32 mwk = ldsM[BUF][rowm*2 + kk]; \
        u32 byte = (mwk >> (g*8)) & 0xffu; \
        u32 x = byte * 0x8001u; \
        u32x4 wv; \
        _Pragma("unroll") \
        for (int pp=0; pp<4; ++pp) wv[pp] = ((x >> (2*pp)) & 0x00010001u) * 0x3F80u; \
        short8 a = __builtin_bit_cast(short8, wv); \
        _Pragma("unroll") \
        for (int nf=0; nf<8; ++nf) \
          acc[mf][nf] = __builtin_amdgcn_mfma_f32_16x16x32_bf16(a, bfrag[nf], acc[mf][nf], 0, 0, 0); \
      } \
    } \
    __builtin_amdgcn_s_setprio(0); \
  } while(0)

#define BODY(CB, SB, T) do { \
    GSTAGE(SB, (T)+2); \
    COMPUTE(CB); \
    VMCNT(3); \
    __builtin_amdgcn_s_barrier(); \
  } while(0)

  GSTAGE(0, 0);
  GSTAGE(1, 1);
  VMCNT(3);
  __builtin_amdgcn_s_barrier();

  #pragma unroll 1
  for (int t = 0; t < 12; t += 3){
    BODY(0, 2, t);
    BODY(1, 0, t+1);
    BODY(2, 1, t+2);
  }
  BODY(0, 2, 12);
  BODY(1, 0, 13);
  COMPUTE(2);
  VMCNT(0);
  __builtin_amdgcn_s_barrier();
  COMPUTE(0);

#undef GSTAGE
#undef COMPUTE
#undef BODY

  u16* dst = part + (size_t)zz * (NN*256);
  #pragma unroll
  for (int mf=0; mf<2; mf++)
    #pragma unroll
    for (int nf=0; nf<8; nf++)
      #pragma unroll
      for (int q=0;q<4;q++){
        int row = m0 + wid*32 + mf*16 + g*4 + q;
        int col = n0 + nf*16 + r;
        dst[row*256 + col] = f2bf(acc[mf][nf][q]);
      }
}

// ---- K5: out = bias + sum_z bf16 partial[z] ----
__global__ __launch_bounds__(256) void k_reduce(const u16* __restrict__ part, const float* __restrict__ bias,
                                                float* __restrict__ out){
  int i = blockIdx.x*256 + threadIdx.x;
  float4 bb = reinterpret_cast<const float4*>(bias)[i & 63];
  float a0 = bb.x, a1 = bb.y, a2 = bb.z, a3 = bb.w;
  #pragma unroll
  for (int z=0; z<8; ++z){
    u64 v = *reinterpret_cast<const u64*>(part + (size_t)z*2097152 + (size_t)i*4);
    a0 += bf2f((u16)(v      ));
    a1 += bf2f((u16)(v >> 16));
    a2 += bf2f((u16)(v >> 32));
    a3 += bf2f((u16)(v >> 48));
  }
  float4 o; o.x=a0; o.y=a1; o.z=a2; o.w=a3;
  reinterpret_cast<float4*>(out)[i] = o;
}

extern "C" void kernel_launch(void* const* d_in, const int* in_sizes, int n_in,
                              void* d_out, int out_size, void* d_ws, size_t ws_size,
                              hipStream_t stream) {
  const float* X    = (const float*)d_in[0];
  const float* S    = (const float*)d_in[1];
  const float* W    = (const float*)d_in[2];
  const float* bias = (const float*)d_in[3];
  float* out = (float*)d_out;
  char* ws = (char*)d_ws;
  u32*   maskT  = (u32*)(ws + 0);          //  8 MiB  [256 jwords][8192 i]
  u16*   Yt     = (u16*)(ws + 8388608);    //  4 MiB  bf16 [256 f][8192 j]
  u16*   snT    = (u16*)(ws + 12582912);   // 512 KiB bf16 hi/lo split, fragment-major
  u32*   degcnt = (u32*)(ws + 13107200);   //  32 KiB integer degrees
  u16*   part   = (u16*)(ws + 13139968);   //  32 MiB bf16 [8][8192][256]

  hipMemsetAsync(degcnt, 0, 8192*sizeof(u32), stream);
  k_norm  <<<dim3(32),   dim3(256), 0, stream>>>(S, snT);
  k_maskM2<<<dim3(1024), dim3(256), 0, stream>>>(snT, maskT, degcnt);
  k_ygemm <<<dim3(8,64), dim3(128), 0, stream>>>(X, W, degcnt, Yt);
  k_agg   <<<dim3(512),  dim3(512), 0, stream>>>(Yt, maskT, part);
  k_reduce<<<dim3(2048), dim3(256), 0, stream>>>(part, bias, out);
}